// Round 4
// baseline (2421.519 us; speedup 1.0000x reference)
//
#include <hip/hip_runtime.h>
#include <hip/hip_bf16.h>

// Swin block: B=64, H=W=56, C=128, WS=7, SHIFT=3, NH=4, hd=32, hidden=512
// Tokens: 200704. Windows: 4096, L=49. fp32 accumulate; external dtype (bf16 OR
// fp32) detected at runtime from norm1_g (all-ones): u16[0]==0x3F80 -> bf16.
// Intermediates are fp32 in ws. Straight pipeline (no residuals); rows stay in
// window order; un-partition scatter fused into fc2 epilogue.
// ws layout: [0,4) flag, [64, 64+rows*512) bufA fp32[rows,128],
//            [64+rows*512, 64+rows*2560) bufB fp32[rows,512].

#define NWIN 4096

__device__ __forceinline__ float bfbits(unsigned short u) {
    union { unsigned int i; float f; } c; c.i = ((unsigned int)u) << 16; return c.f;
}
__device__ __forceinline__ unsigned short f2bf(float v) {
    __hip_bfloat16 h = __float2bfloat16(v);
    return *reinterpret_cast<unsigned short*>(&h);
}
// f==0: external buffer is bf16 ; f==1: fp32
__device__ __forceinline__ float ldg_f(const void* p, size_t i, int f) {
    return f ? ((const float*)p)[i] : bfbits(((const unsigned short*)p)[i]);
}
__device__ __forceinline__ void st_f(void* p, size_t i, int f, float v) {
    if (f) ((float*)p)[i] = v; else ((unsigned short*)p)[i] = f2bf(v);
}

__global__ void detect_kernel(const unsigned short* g, int* flag) {
    *flag = (g[0] == 0x3F80u) ? 0 : 1;
}

// mode 0: LN1 — in = x (external dtype), source = roll(3,3)+window-partition of
//         global token (tbase+local); out = bufA fp32 (window order, local rows).
// mode 1: LN2 — in = fp32 intermediate, plain per-row; out fp32.
__global__ __launch_bounds__(256) void ln_kernel(
    const void* __restrict__ in,
    const void* __restrict__ g,
    const void* __restrict__ bta,
    float* __restrict__ out, int mode, int tbase, const int* __restrict__ flagp)
{
    int f = *flagp;
    int in_f = (mode == 0) ? f : 1;
    int tid = threadIdx.x;
    int wave = tid >> 6, lane = tid & 63;
    int local = blockIdx.x * 4 + wave;

    int in_row;
    if (mode == 0) {
        int t = tbase + local;
        int n = t / 49, l = t - n * 49;
        int b = n >> 6, wh = (n >> 3) & 7, ww = n & 7;
        int i = l / 7, j = l - i * 7;
        int hh = wh * 7 + i, wimg = ww * 7 + j;
        int sh = (hh + 53) % 56, sw = (wimg + 53) % 56;  // roll(3,3): src = idx-3 mod 56
        in_row = (b * 56 + sh) * 56 + sw;
    } else {
        in_row = local;
    }

    size_t ib = (size_t)in_row * 128;
    float v0 = ldg_f(in, ib + lane, in_f);
    float v1 = ldg_f(in, ib + lane + 64, in_f);
    float s = v0 + v1, sq = v0 * v0 + v1 * v1;
    #pragma unroll
    for (int off = 32; off > 0; off >>= 1) {
        s  += __shfl_xor(s, off);
        sq += __shfl_xor(sq, off);
    }
    float mean = s * (1.0f / 128.0f);
    float var  = sq * (1.0f / 128.0f) - mean * mean;
    float rstd = rsqrtf(var + 1e-5f);
    float g0 = ldg_f(g, lane, f),        g1 = ldg_f(g, lane + 64, f);
    float c0 = ldg_f(bta, lane, f),      c1 = ldg_f(bta, lane + 64, f);
    float* op = out + (size_t)local * 128;
    op[lane]      = (v0 - mean) * rstd * g0 + c0;
    op[lane + 64] = (v1 - mean) * rstd * g1 + c1;
}

// Out[M,N] = A[M,K] @ W[N,K]^T + bias; act=1 -> exact GELU.
// A is fp32 intermediate. W/bias external (flag). remap=0: Out fp32 intermediate;
// remap=1: Out = d_out (external dtype), rows scattered to image order.
// BM=BN=64, BK=16, 256 threads, 4x4 tile. N mult of 64, K mult of 16; M guarded.
__global__ __launch_bounds__(256) void gemm_kernel(
    const float* __restrict__ A,
    const void* __restrict__ W,
    const void* __restrict__ bias,
    void* __restrict__ Out,
    int M, int N, int K, int act, int remap, int tbase, const int* __restrict__ flagp)
{
    int f = *flagp;
    int out_f = remap ? f : 1;
    __shared__ float As[16][65];
    __shared__ float Bs[16][65];
    int tid = threadIdx.x;
    int tx = tid & 15, ty = tid >> 4;
    int m0 = blockIdx.y * 64, n0 = blockIdx.x * 64;

    int lr = tid >> 2;          // row 0..63
    int lk = (tid & 3) * 4;     // k offset {0,4,8,12}
    int ar = m0 + lr; if (ar >= M) ar = M - 1;   // clamp (guarded at epilogue)

    float acc[4][4] = {};
    for (int k0 = 0; k0 < K; k0 += 16) {
        float4 av = *reinterpret_cast<const float4*>(A + (size_t)ar * K + k0 + lk);
        size_t wb = (size_t)(n0 + lr) * K + k0 + lk;
        As[lk + 0][lr] = av.x;
        As[lk + 1][lr] = av.y;
        As[lk + 2][lr] = av.z;
        As[lk + 3][lr] = av.w;
        Bs[lk + 0][lr] = ldg_f(W, wb + 0, f);
        Bs[lk + 1][lr] = ldg_f(W, wb + 1, f);
        Bs[lk + 2][lr] = ldg_f(W, wb + 2, f);
        Bs[lk + 3][lr] = ldg_f(W, wb + 3, f);
        __syncthreads();
        #pragma unroll
        for (int k = 0; k < 16; ++k) {
            float a[4], bb[4];
            #pragma unroll
            for (int ii = 0; ii < 4; ++ii) a[ii] = As[k][ty * 4 + ii];
            #pragma unroll
            for (int jj = 0; jj < 4; ++jj) bb[jj] = Bs[k][tx * 4 + jj];
            #pragma unroll
            for (int ii = 0; ii < 4; ++ii)
                #pragma unroll
                for (int jj = 0; jj < 4; ++jj)
                    acc[ii][jj] += a[ii] * bb[jj];
        }
        __syncthreads();
    }
    #pragma unroll
    for (int jj = 0; jj < 4; ++jj) {
        int nn = n0 + tx * 4 + jj;
        float bv = ldg_f(bias, nn, f);
        #pragma unroll
        for (int ii = 0; ii < 4; ++ii) {
            int m = m0 + ty * 4 + ii;
            if (m >= M) continue;
            float v = acc[ii][jj] + bv;
            if (act == 1) v = 0.5f * v * (1.0f + erff(v * 0.70710678118654752f));
            size_t orow;
            if (remap) {
                int t = tbase + m;
                int n = t / 49, l = t - n * 49;
                int b = n >> 6, wh = (n >> 3) & 7, ww = n & 7;
                int i = l / 7, j = l - i * 7;
                orow = (size_t)((b * 56 + wh * 7 + i) * 56 + ww * 7 + j);
            } else {
                orow = (size_t)m;
            }
            st_f(Out, orow * N + nn, out_f, v);
        }
    }
}

// One block per (local window n, head h). qkv fp32 [wpc,49,384], o fp32 [wpc,49,128].
__global__ __launch_bounds__(256) void attn_kernel(
    const float* __restrict__ qkv,
    const void* __restrict__ pe,   // [4,169] external
    float* __restrict__ o, const int* __restrict__ flagp)
{
    int f = *flagp;
    __shared__ float qs[49 * 33];
    __shared__ float ks[49 * 33];
    __shared__ float vs[49 * 33];
    __shared__ float sc[49 * 49];
    int n = blockIdx.x >> 2;
    int h = blockIdx.x & 3;
    int tid = threadIdx.x;
    const float* base = qkv + (size_t)n * 49 * 384 + h * 32;
    for (int idx = tid; idx < 1568; idx += 256) {
        int l = idx >> 5, d = idx & 31;
        const float* p = base + (size_t)l * 384 + d;
        qs[l * 33 + d] = p[0];
        ks[l * 33 + d] = p[128];
        vs[l * 33 + d] = p[256];
    }
    __syncthreads();
    for (int pi = tid; pi < 2401; pi += 256) {
        int l1 = pi / 49, l2 = pi - l1 * 49;
        float dot = 0.f;
        #pragma unroll
        for (int d = 0; d < 32; ++d) dot += qs[l1 * 33 + d] * ks[l2 * 33 + d];
        int i1 = l1 / 7, j1 = l1 - i1 * 7, i2 = l2 / 7, j2 = l2 - i2 * 7;
        int ridx = (i1 - i2 + 6) * 13 + (j1 - j2 + 6);
        sc[pi] = dot * 0.17677669529663687f + ldg_f(pe, h * 169 + ridx, f);
    }
    __syncthreads();
    if (tid < 49) {
        float mx = -1e30f;
        for (int l2 = 0; l2 < 49; ++l2) mx = fmaxf(mx, sc[tid * 49 + l2]);
        float ssum = 0.f;
        for (int l2 = 0; l2 < 49; ++l2) {
            float e = __expf(sc[tid * 49 + l2] - mx);
            sc[tid * 49 + l2] = e; ssum += e;
        }
        float inv = 1.0f / ssum;
        for (int l2 = 0; l2 < 49; ++l2) sc[tid * 49 + l2] *= inv;
    }
    __syncthreads();
    float* ob = o + (size_t)n * 49 * 128 + h * 32;
    for (int idx = tid; idx < 1568; idx += 256) {
        int l1 = idx >> 5, d = idx & 31;
        float s = 0.f;
        for (int l2 = 0; l2 < 49; ++l2) s += sc[l1 * 49 + l2] * vs[l2 * 33 + d];
        ob[(size_t)l1 * 128 + d] = s;
    }
}

extern "C" void kernel_launch(void* const* d_in, const int* in_sizes, int n_in,
                              void* d_out, int out_size, void* d_ws, size_t ws_size,
                              hipStream_t stream) {
    const void* x    = d_in[0];
    const void* n1g  = d_in[1];
    const void* n1b  = d_in[2];
    const void* qkvw = d_in[3];
    const void* qkvb = d_in[4];
    const void* outw = d_in[5];
    const void* outb = d_in[6];
    const void* pe   = d_in[7];
    const void* n2g  = d_in[8];
    const void* n2b  = d_in[9];
    const void* w1   = d_in[10];
    const void* b1   = d_in[11];
    const void* w2   = d_in[12];
    const void* b2   = d_in[13];

    char* ws = (char*)d_ws;
    int* flag = (int*)ws;

    // windows per chunk: largest power of two (>=8) whose fp32 footprint fits.
    size_t wpc = NWIN;
    while (wpc > 8 && 64 + wpc * 49 * 2560 > ws_size) wpc >>= 1;
    const int nchunks = (int)(NWIN / wpc);
    const size_t rows = wpc * 49;

    float* bufA = (float*)(ws + 64);               // rows x 128 fp32
    float* bufB = (float*)(ws + 64 + rows * 512);  // rows x 512 fp32
    const int gy = (int)((rows + 63) / 64);

    detect_kernel<<<1, 1, 0, stream>>>((const unsigned short*)n1g, flag);

    for (int c = 0; c < nchunks; ++c) {
        int tbase = (int)(c * wpc * 49);
        // 1) LN1 + roll + partition: x -> bufA
        ln_kernel<<<(int)(rows / 4), 256, 0, stream>>>(x, n1g, n1b, bufA, 0, tbase, flag);
        // 2) QKV: bufA -> bufB [rows,384]
        gemm_kernel<<<dim3(6, gy), 256, 0, stream>>>(bufA, qkvw, qkvb, bufB, (int)rows, 384, 128, 0, 0, 0, flag);
        // 3) attention: bufB -> bufA [rows,128]
        attn_kernel<<<(int)(wpc * 4), 256, 0, stream>>>(bufB, pe, bufA, flag);
        // 4) out-proj: bufA -> bufB [rows,128]
        gemm_kernel<<<dim3(2, gy), 256, 0, stream>>>(bufA, outw, outb, bufB, (int)rows, 128, 128, 0, 0, 0, flag);
        // 5) LN2 (plain): bufB -> bufA
        ln_kernel<<<(int)(rows / 4), 256, 0, stream>>>(bufB, n2g, n2b, bufA, 1, 0, flag);
        // 6) fc1 + GELU: bufA -> bufB [rows,512]
        gemm_kernel<<<dim3(8, gy), 256, 0, stream>>>(bufA, w1, b1, bufB, (int)rows, 512, 128, 1, 0, 0, flag);
        // 7) fc2 + un-partition scatter -> d_out
        gemm_kernel<<<dim3(2, gy), 256, 0, stream>>>(bufB, w2, b2, d_out, (int)rows, 128, 512, 0, 1, tbase, flag);
    }
}

// Round 5
// 1129.554 us; speedup vs baseline: 2.1438x; 2.1438x over previous
//
#include <hip/hip_runtime.h>
#include <hip/hip_bf16.h>

// Swin block: B=64, H=W=56, C=128, WS=7, SHIFT=3, NH=4, hd=32, hidden=512
// Tokens: 200704. Windows: 4096, L=49. fp32 I/O (confirmed round 4).
// GEMMs use split-bf16 MFMA: a*b ~= ahi*bhi + ahi*blo + alo*bhi (rel err ~2^-16).
// Straight pipeline, rows in window order, un-partition scatter in fc2 epilogue.
// ws: bufA fp32[rows,128] at 0 ; bufB fp32[rows,512] at rows*512 bytes.

#define NWIN 4096
#define STR 40   // LDS row stride in bf16 units (80 B = 20 banks; 2-way alias = free)

typedef __attribute__((ext_vector_type(8))) short s8v;
typedef __attribute__((ext_vector_type(4))) float f4v;

__device__ __forceinline__ void split2(float v, unsigned short& h, unsigned short& l) {
    unsigned int b = __float_as_uint(v);
    h = (unsigned short)(b >> 16);                       // truncated hi
    float hf = __uint_as_float(b & 0xFFFF0000u);
    __hip_bfloat16 lo = __float2bfloat16(v - hf);        // exact residual, RNE to bf16
    l = *reinterpret_cast<unsigned short*>(&lo);
}

// mode 0: LN1 — read x (image order) at roll(3,3)+window-partition source for
//         global token tbase+local; write bufA fp32 local row (window order).
// mode 1: LN2 — plain per-row LN, fp32 in/out.
__global__ __launch_bounds__(256) void ln_kernel(
    const float* __restrict__ in,
    const float* __restrict__ g,
    const float* __restrict__ bta,
    float* __restrict__ out, int mode, int tbase)
{
    int tid = threadIdx.x;
    int wave = tid >> 6, lane = tid & 63;
    int local = blockIdx.x * 4 + wave;

    int in_row;
    if (mode == 0) {
        int t = tbase + local;
        int n = t / 49, l = t - n * 49;
        int b = n >> 6, wh = (n >> 3) & 7, ww = n & 7;
        int i = l / 7, j = l - i * 7;
        int hh = wh * 7 + i, wimg = ww * 7 + j;
        int sh = (hh + 53) % 56, sw = (wimg + 53) % 56;  // roll(3,3): src = idx-3 mod 56
        in_row = (b * 56 + sh) * 56 + sw;
    } else {
        in_row = local;
    }

    const float* ip = in + (size_t)in_row * 128;
    float v0 = ip[lane], v1 = ip[lane + 64];
    float s = v0 + v1, sq = v0 * v0 + v1 * v1;
    #pragma unroll
    for (int off = 32; off > 0; off >>= 1) {
        s  += __shfl_xor(s, off);
        sq += __shfl_xor(sq, off);
    }
    float mean = s * (1.0f / 128.0f);
    float var  = sq * (1.0f / 128.0f) - mean * mean;
    float rstd = rsqrtf(var + 1e-5f);
    float* op = out + (size_t)local * 128;
    op[lane]      = (v0 - mean) * rstd * g[lane]      + bta[lane];
    op[lane + 64] = (v1 - mean) * rstd * g[lane + 64] + bta[lane + 64];
}

// Out[M,N] = A[M,K] @ W[N,K]^T + bias; act=1 -> exact GELU; remap=1 -> scatter
// rows to image order (window un-partition). Split-bf16 MFMA, fp32 accumulate.
// Block 64x64, BK=32, 4 waves each 32x32. N mult of 64, K mult of 32; M guarded.
__global__ __launch_bounds__(256) void gemm_mfma(
    const float* __restrict__ A,
    const float* __restrict__ W,
    const float* __restrict__ bias,
    float* __restrict__ Out,
    int M, int N, int K, int act, int remap, int tbase)
{
    __shared__ unsigned short Ah[64 * STR];
    __shared__ unsigned short Al[64 * STR];
    __shared__ unsigned short Wh[64 * STR];
    __shared__ unsigned short Wl[64 * STR];
    int tid = threadIdx.x;
    int wv = tid >> 6, ln = tid & 63;
    int wm = wv & 1, wn = wv >> 1;          // wave quadrant in 64x64
    int fm = ln & 15, fq = ln >> 4;         // fragment row / quad
    int m0 = blockIdx.y * 64, n0 = blockIdx.x * 64;

    int sr = tid >> 2, sk = (tid & 3) * 8;  // staging: row 0..63, k offset {0,8,16,24}
    int arow = m0 + sr; if (arow >= M) arow = M - 1;
    const float* Ap = A + (size_t)arow * K + sk;
    const float* Wp = W + (size_t)(n0 + sr) * K + sk;

    f4v acc[2][2] = {};

    for (int k0 = 0; k0 < K; k0 += 32) {
        #pragma unroll
        for (int h = 0; h < 2; ++h) {
            float4 a4 = *reinterpret_cast<const float4*>(Ap + k0 + h * 4);
            float4 w4 = *reinterpret_cast<const float4*>(Wp + k0 + h * 4);
            ushort4 ah, al, wh, wl;
            split2(a4.x, ah.x, al.x); split2(a4.y, ah.y, al.y);
            split2(a4.z, ah.z, al.z); split2(a4.w, ah.w, al.w);
            split2(w4.x, wh.x, wl.x); split2(w4.y, wh.y, wl.y);
            split2(w4.z, wh.z, wl.z); split2(w4.w, wh.w, wl.w);
            int off = sr * STR + sk + h * 4;
            *reinterpret_cast<ushort4*>(&Ah[off]) = ah;
            *reinterpret_cast<ushort4*>(&Al[off]) = al;
            *reinterpret_cast<ushort4*>(&Wh[off]) = wh;
            *reinterpret_cast<ushort4*>(&Wl[off]) = wl;
        }
        __syncthreads();
        s8v a_h[2], a_l[2], b_h[2], b_l[2];
        #pragma unroll
        for (int t = 0; t < 2; ++t) {
            int ao = (wm * 32 + t * 16 + fm) * STR + fq * 8;
            a_h[t] = *reinterpret_cast<const s8v*>(&Ah[ao]);
            a_l[t] = *reinterpret_cast<const s8v*>(&Al[ao]);
            int bo = (wn * 32 + t * 16 + fm) * STR + fq * 8;
            b_h[t] = *reinterpret_cast<const s8v*>(&Wh[bo]);
            b_l[t] = *reinterpret_cast<const s8v*>(&Wl[bo]);
        }
        #pragma unroll
        for (int tm = 0; tm < 2; ++tm)
            #pragma unroll
            for (int tn = 0; tn < 2; ++tn) {
                acc[tm][tn] = __builtin_amdgcn_mfma_f32_16x16x32_bf16(a_h[tm], b_h[tn], acc[tm][tn], 0, 0, 0);
                acc[tm][tn] = __builtin_amdgcn_mfma_f32_16x16x32_bf16(a_h[tm], b_l[tn], acc[tm][tn], 0, 0, 0);
                acc[tm][tn] = __builtin_amdgcn_mfma_f32_16x16x32_bf16(a_l[tm], b_h[tn], acc[tm][tn], 0, 0, 0);
            }
        __syncthreads();
    }

    #pragma unroll
    for (int tm = 0; tm < 2; ++tm) {
        #pragma unroll
        for (int tn = 0; tn < 2; ++tn) {
            int col = n0 + wn * 32 + tn * 16 + fm;
            float bv = bias[col];
            #pragma unroll
            for (int r = 0; r < 4; ++r) {
                int m = m0 + wm * 32 + tm * 16 + fq * 4 + r;
                if (m >= M) continue;
                float v = acc[tm][tn][r] + bv;
                if (act) v = 0.5f * v * (1.0f + erff(v * 0.70710678118654752f));
                size_t orow;
                if (remap) {
                    int t = tbase + m;
                    int n = t / 49, l = t - n * 49;
                    int b = n >> 6, wh = (n >> 3) & 7, ww = n & 7;
                    int i = l / 7, j = l - i * 7;
                    orow = (size_t)((b * 56 + wh * 7 + i) * 56 + ww * 7 + j);
                } else {
                    orow = (size_t)m;
                }
                Out[orow * N + col] = v;
            }
        }
    }
}

// One block per (local window n, head h). qkv fp32 [wpc,49,384], o fp32 [wpc,49,128].
__global__ __launch_bounds__(256) void attn_kernel(
    const float* __restrict__ qkv,
    const float* __restrict__ pe,   // [4,169]
    float* __restrict__ o)
{
    __shared__ float qs[49 * 33];
    __shared__ float ks[49 * 33];
    __shared__ float vs[49 * 33];
    __shared__ float sc[49 * 49];
    int n = blockIdx.x >> 2;
    int h = blockIdx.x & 3;
    int tid = threadIdx.x;
    const float* base = qkv + (size_t)n * 49 * 384 + h * 32;
    for (int idx = tid; idx < 1568; idx += 256) {
        int l = idx >> 5, d = idx & 31;
        const float* p = base + (size_t)l * 384 + d;
        qs[l * 33 + d] = p[0];
        ks[l * 33 + d] = p[128];
        vs[l * 33 + d] = p[256];
    }
    __syncthreads();
    for (int pi = tid; pi < 2401; pi += 256) {
        int l1 = pi / 49, l2 = pi - l1 * 49;
        float dot = 0.f;
        #pragma unroll
        for (int d = 0; d < 32; ++d) dot += qs[l1 * 33 + d] * ks[l2 * 33 + d];
        int i1 = l1 / 7, j1 = l1 - i1 * 7, i2 = l2 / 7, j2 = l2 - i2 * 7;
        int ridx = (i1 - i2 + 6) * 13 + (j1 - j2 + 6);
        sc[pi] = dot * 0.17677669529663687f + pe[h * 169 + ridx];
    }
    __syncthreads();
    if (tid < 49) {
        float mx = -1e30f;
        for (int l2 = 0; l2 < 49; ++l2) mx = fmaxf(mx, sc[tid * 49 + l2]);
        float ssum = 0.f;
        for (int l2 = 0; l2 < 49; ++l2) {
            float e = __expf(sc[tid * 49 + l2] - mx);
            sc[tid * 49 + l2] = e; ssum += e;
        }
        float inv = 1.0f / ssum;
        for (int l2 = 0; l2 < 49; ++l2) sc[tid * 49 + l2] *= inv;
    }
    __syncthreads();
    float* ob = o + (size_t)n * 49 * 128 + h * 32;
    for (int idx = tid; idx < 1568; idx += 256) {
        int l1 = idx >> 5, d = idx & 31;
        float s = 0.f;
        for (int l2 = 0; l2 < 49; ++l2) s += sc[l1 * 49 + l2] * vs[l2 * 33 + d];
        ob[(size_t)l1 * 128 + d] = s;
    }
}

extern "C" void kernel_launch(void* const* d_in, const int* in_sizes, int n_in,
                              void* d_out, int out_size, void* d_ws, size_t ws_size,
                              hipStream_t stream) {
    const float* x    = (const float*)d_in[0];
    const float* n1g  = (const float*)d_in[1];
    const float* n1b  = (const float*)d_in[2];
    const float* qkvw = (const float*)d_in[3];
    const float* qkvb = (const float*)d_in[4];
    const float* outw = (const float*)d_in[5];
    const float* outb = (const float*)d_in[6];
    const float* pe   = (const float*)d_in[7];
    const float* n2g  = (const float*)d_in[8];
    const float* n2b  = (const float*)d_in[9];
    const float* w1   = (const float*)d_in[10];
    const float* b1   = (const float*)d_in[11];
    const float* w2   = (const float*)d_in[12];
    const float* b2   = (const float*)d_in[13];
    float* y = (float*)d_out;

    // windows per chunk: largest power of two whose fp32 footprint fits ws.
    size_t wpc = NWIN;
    while (wpc > 8 && wpc * 49 * 2560 > ws_size) wpc >>= 1;
    const int nchunks = (int)(NWIN / wpc);
    const size_t rows = wpc * 49;

    char* ws = (char*)d_ws;
    float* bufA = (float*)ws;                    // rows x 128 fp32
    float* bufB = (float*)(ws + rows * 512);     // rows x 512 fp32
    const int gy = (int)((rows + 63) / 64);

    for (int c = 0; c < nchunks; ++c) {
        int tbase = (int)(c * wpc * 49);
        // 1) LN1 + roll + partition: x -> bufA
        ln_kernel<<<(int)(rows / 4), 256, 0, stream>>>(x, n1g, n1b, bufA, 0, tbase);
        // 2) QKV: bufA -> bufB [rows,384]
        gemm_mfma<<<dim3(6, gy), 256, 0, stream>>>(bufA, qkvw, qkvb, bufB, (int)rows, 384, 128, 0, 0, 0);
        // 3) attention: bufB -> bufA [rows,128]
        attn_kernel<<<(int)(wpc * 4), 256, 0, stream>>>(bufB, pe, bufA);
        // 4) out-proj: bufA -> bufB [rows,128]
        gemm_mfma<<<dim3(2, gy), 256, 0, stream>>>(bufA, outw, outb, bufB, (int)rows, 128, 128, 0, 0, 0);
        // 5) LN2 (plain): bufB -> bufA
        ln_kernel<<<(int)(rows / 4), 256, 0, stream>>>(bufB, n2g, n2b, bufA, 1, 0);
        // 6) fc1 + GELU: bufA -> bufB [rows,512]
        gemm_mfma<<<dim3(8, gy), 256, 0, stream>>>(bufA, w1, b1, bufB, (int)rows, 512, 128, 1, 0, 0);
        // 7) fc2 + un-partition scatter -> d_out
        gemm_mfma<<<dim3(2, gy), 256, 0, stream>>>(bufB, w2, b2, y, (int)rows, 128, 512, 0, 1, tbase);
    }
}

// Round 6
// 948.975 us; speedup vs baseline: 2.5517x; 1.1903x over previous
//
#include <hip/hip_runtime.h>
#include <hip/hip_bf16.h>

// Swin block: B=64, H=W=56, C=128, WS=7, SHIFT=3, NH=4, hd=32, hidden=512
// Tokens: 200704. Windows: 4096, L=49. fp32 I/O.
// GEMMs: split-bf16 MFMA (3-term). Attention: pure-bf16 MFMA (scores sigma~0.3,
// error contribution ~2e-4 on y). Straight pipeline, window order, scatter in fc2.
// ws: [0,64K) bias table (C-layout), bufA fp32[rows,128], bufB fp32[rows,512].

#define NWIN 4096
#define STR 40   // GEMM LDS stride (bf16 units); 80 B -> 2-way bank alias = free

typedef __attribute__((ext_vector_type(8))) short s8v;
typedef __attribute__((ext_vector_type(4))) float f4v;

__device__ __forceinline__ void split2(float v, unsigned short& h, unsigned short& l) {
    unsigned int b = __float_as_uint(v);
    h = (unsigned short)(b >> 16);                       // truncated hi
    float hf = __uint_as_float(b & 0xFFFF0000u);
    __hip_bfloat16 lo = __float2bfloat16(v - hf);        // exact residual, RNE
    l = *reinterpret_cast<unsigned short*>(&lo);
}
__device__ __forceinline__ unsigned short bfr(float v) {  // RNE bf16 bits
    __hip_bfloat16 h = __float2bfloat16(v);
    return *reinterpret_cast<unsigned short*>(&h);
}

// ---------------- LN (modes as before) ----------------
__global__ __launch_bounds__(256) void ln_kernel(
    const float* __restrict__ in, const float* __restrict__ g,
    const float* __restrict__ bta, float* __restrict__ out, int mode, int tbase)
{
    int tid = threadIdx.x;
    int wave = tid >> 6, lane = tid & 63;
    int local = blockIdx.x * 4 + wave;
    int in_row;
    if (mode == 0) {
        int t = tbase + local;
        int n = t / 49, l = t - n * 49;
        int b = n >> 6, wh = (n >> 3) & 7, ww = n & 7;
        int i = l / 7, j = l - i * 7;
        int hh = wh * 7 + i, wimg = ww * 7 + j;
        int sh = (hh + 53) % 56, sw = (wimg + 53) % 56;
        in_row = (b * 56 + sh) * 56 + sw;
    } else in_row = local;

    const float* ip = in + (size_t)in_row * 128;
    float v0 = ip[lane], v1 = ip[lane + 64];
    float s = v0 + v1, sq = v0 * v0 + v1 * v1;
    #pragma unroll
    for (int off = 32; off > 0; off >>= 1) { s += __shfl_xor(s, off); sq += __shfl_xor(sq, off); }
    float mean = s * (1.0f / 128.0f);
    float var  = sq * (1.0f / 128.0f) - mean * mean;
    float rstd = rsqrtf(var + 1e-5f);
    float* op = out + (size_t)local * 128;
    op[lane]      = (v0 - mean) * rstd * g[lane]      + bta[lane];
    op[lane + 64] = (v1 - mean) * rstd * g[lane + 64] + bta[lane + 64];
}

// ---------------- GEMM (split-bf16 MFMA, unchanged from round 5) ----------------
__global__ __launch_bounds__(256) void gemm_mfma(
    const float* __restrict__ A, const float* __restrict__ W,
    const float* __restrict__ bias, float* __restrict__ Out,
    int M, int N, int K, int act, int remap, int tbase)
{
    __shared__ unsigned short Ah[64 * STR];
    __shared__ unsigned short Al[64 * STR];
    __shared__ unsigned short Wh[64 * STR];
    __shared__ unsigned short Wl[64 * STR];
    int tid = threadIdx.x;
    int wv = tid >> 6, ln = tid & 63;
    int wm = wv & 1, wn = wv >> 1;
    int fm = ln & 15, fq = ln >> 4;
    int m0 = blockIdx.y * 64, n0 = blockIdx.x * 64;
    int sr = tid >> 2, sk = (tid & 3) * 8;
    int arow = m0 + sr; if (arow >= M) arow = M - 1;
    const float* Ap = A + (size_t)arow * K + sk;
    const float* Wp = W + (size_t)(n0 + sr) * K + sk;

    f4v acc[2][2] = {};
    for (int k0 = 0; k0 < K; k0 += 32) {
        #pragma unroll
        for (int h = 0; h < 2; ++h) {
            float4 a4 = *reinterpret_cast<const float4*>(Ap + k0 + h * 4);
            float4 w4 = *reinterpret_cast<const float4*>(Wp + k0 + h * 4);
            ushort4 ah, al, wh, wl;
            split2(a4.x, ah.x, al.x); split2(a4.y, ah.y, al.y);
            split2(a4.z, ah.z, al.z); split2(a4.w, ah.w, al.w);
            split2(w4.x, wh.x, wl.x); split2(w4.y, wh.y, wl.y);
            split2(w4.z, wh.z, wl.z); split2(w4.w, wh.w, wl.w);
            int off = sr * STR + sk + h * 4;
            *reinterpret_cast<ushort4*>(&Ah[off]) = ah;
            *reinterpret_cast<ushort4*>(&Al[off]) = al;
            *reinterpret_cast<ushort4*>(&Wh[off]) = wh;
            *reinterpret_cast<ushort4*>(&Wl[off]) = wl;
        }
        __syncthreads();
        s8v a_h[2], a_l[2], b_h[2], b_l[2];
        #pragma unroll
        for (int t = 0; t < 2; ++t) {
            int ao = (wm * 32 + t * 16 + fm) * STR + fq * 8;
            a_h[t] = *reinterpret_cast<const s8v*>(&Ah[ao]);
            a_l[t] = *reinterpret_cast<const s8v*>(&Al[ao]);
            int bo = (wn * 32 + t * 16 + fm) * STR + fq * 8;
            b_h[t] = *reinterpret_cast<const s8v*>(&Wh[bo]);
            b_l[t] = *reinterpret_cast<const s8v*>(&Wl[bo]);
        }
        #pragma unroll
        for (int tm = 0; tm < 2; ++tm)
            #pragma unroll
            for (int tn = 0; tn < 2; ++tn) {
                acc[tm][tn] = __builtin_amdgcn_mfma_f32_16x16x32_bf16(a_h[tm], b_h[tn], acc[tm][tn], 0, 0, 0);
                acc[tm][tn] = __builtin_amdgcn_mfma_f32_16x16x32_bf16(a_h[tm], b_l[tn], acc[tm][tn], 0, 0, 0);
                acc[tm][tn] = __builtin_amdgcn_mfma_f32_16x16x32_bf16(a_l[tm], b_h[tn], acc[tm][tn], 0, 0, 0);
            }
        __syncthreads();
    }
    #pragma unroll
    for (int tm = 0; tm < 2; ++tm)
        #pragma unroll
        for (int tn = 0; tn < 2; ++tn) {
            int col = n0 + wn * 32 + tn * 16 + fm;
            float bv = bias[col];
            #pragma unroll
            for (int r = 0; r < 4; ++r) {
                int m = m0 + wm * 32 + tm * 16 + fq * 4 + r;
                if (m >= M) continue;
                float v = acc[tm][tn][r] + bv;
                if (act) v = 0.5f * v * (1.0f + erff(v * 0.70710678118654752f));
                size_t orow;
                if (remap) {
                    int t = tbase + m;
                    int n = t / 49, l = t - n * 49;
                    int b = n >> 6, wh = (n >> 3) & 7, ww = n & 7;
                    int i = l / 7, j = l - i * 7;
                    orow = (size_t)((b * 56 + wh * 7 + i) * 56 + ww * 7 + j);
                } else orow = (size_t)m;
                Out[orow * N + col] = v;
            }
        }
}

// ---------------- bias table in MFMA C-layout: [4][64 lanes][16 (mt,nt)][4 r] ----------------
__global__ void bias_tab_kernel(const float* __restrict__ pe, float* __restrict__ tab) {
    int t = threadIdx.x;          // 256 = 4 heads x 64 lanes
    int h = t >> 6, ln = t & 63;
    int g = ln >> 4, c = ln & 15;
    for (int mt = 0; mt < 4; ++mt)
        for (int nt = 0; nt < 4; ++nt)
            for (int r = 0; r < 4; ++r) {
                int l1 = mt * 16 + g * 4 + r, l2 = nt * 16 + c;
                float b = 0.f;
                if (l1 < 49 && l2 < 49) {
                    int i1 = l1 / 7, j1 = l1 % 7, i2 = l2 / 7, j2 = l2 % 7;
                    b = pe[h * 169 + (i1 - i2 + 6) * 13 + (j1 - j2 + 6)];
                }
                tab[((h * 64 + ln) * 16 + mt * 4 + nt) * 4 + r] = b;
            }
}

// ---------------- MFMA attention: one block per window, wave = head ----------------
// Per-head LDS (shorts): Q[64*40]  K[64*40]  V^T[32*72]; P[64*72] aliases Q+K.
#define HB 7424   // per-head shorts: 2560 + 2560 + 2304
__global__ __launch_bounds__(256) void attn_mfma(
    const float* __restrict__ qkv,      // [wpc,49,384]
    const float* __restrict__ btab,     // [4][64][16][4]
    float* __restrict__ o)              // [wpc,49,128]
{
    __shared__ unsigned short lds[4 * HB];
    int tid = threadIdx.x;
    int win = blockIdx.x;
    const float* src = qkv + (size_t)win * 49 * 384;

    // zero V^T pad cols l2=49..63 (4 heads x 32 d x 15)
    for (int i = tid; i < 1920; i += 256) {
        int h = i / 480, rem = i % 480, d = rem / 15, l2 = 49 + rem % 15;
        lds[h * HB + 5120 + d * 72 + l2] = 0;
    }
    // stage QKV -> bf16 LDS (Q scaled by 1/sqrt(32))
    for (int idx = tid; idx < 4704; idx += 256) {
        int l2 = idx / 96, c4 = idx - l2 * 96;
        int d4 = c4 * 4;
        float4 v4 = *reinterpret_cast<const float4*>(src + (size_t)l2 * 384 + d4);
        int sec = d4 >> 7, dd = d4 & 127, h = dd >> 5, kk = dd & 31;
        int base = h * HB;
        if (sec == 0) {
            ushort4 u = { bfr(v4.x * 0.17677669529663687f), bfr(v4.y * 0.17677669529663687f),
                          bfr(v4.z * 0.17677669529663687f), bfr(v4.w * 0.17677669529663687f) };
            *reinterpret_cast<ushort4*>(&lds[base + l2 * 40 + kk]) = u;
        } else if (sec == 1) {
            ushort4 u = { bfr(v4.x), bfr(v4.y), bfr(v4.z), bfr(v4.w) };
            *reinterpret_cast<ushort4*>(&lds[base + 2560 + l2 * 40 + kk]) = u;
        } else {
            lds[base + 5120 + (kk + 0) * 72 + l2] = bfr(v4.x);
            lds[base + 5120 + (kk + 1) * 72 + l2] = bfr(v4.y);
            lds[base + 5120 + (kk + 2) * 72 + l2] = bfr(v4.z);
            lds[base + 5120 + (kk + 3) * 72 + l2] = bfr(v4.w);
        }
    }
    __syncthreads();

    int h = tid >> 6, ln = tid & 63;
    int fm = ln & 15, fq = ln >> 4;
    int base = h * HB;

    // S = Q @ K^T  (+ bias from table)
    s8v Qf[4], Kf[4];
    #pragma unroll
    for (int t = 0; t < 4; ++t) {
        Qf[t] = *reinterpret_cast<const s8v*>(&lds[base + (t * 16 + fm) * 40 + fq * 8]);
        Kf[t] = *reinterpret_cast<const s8v*>(&lds[base + 2560 + (t * 16 + fm) * 40 + fq * 8]);
    }
    f4v S[4][4] = {};
    #pragma unroll
    for (int mt = 0; mt < 4; ++mt)
        #pragma unroll
        for (int nt = 0; nt < 4; ++nt)
            S[mt][nt] = __builtin_amdgcn_mfma_f32_16x16x32_bf16(Qf[mt], Kf[nt], S[mt][nt], 0, 0, 0);
    #pragma unroll
    for (int mt = 0; mt < 4; ++mt)
        #pragma unroll
        for (int nt = 0; nt < 4; ++nt)
            S[mt][nt] += *reinterpret_cast<const f4v*>(&btab[((h * 64 + ln) * 16 + mt * 4 + nt) * 4]);

    // in-register softmax per row (rows live in 16-lane shuffle groups); P -> LDS (aliases Q+K)
    float rcp[16];
    #pragma unroll
    for (int mt = 0; mt < 4; ++mt) {
        #pragma unroll
        for (int r = 0; r < 4; ++r) {
            float v0 = S[mt][0][r], v1 = S[mt][1][r], v2 = S[mt][2][r], v3 = S[mt][3][r];
            if (fm != 0) v3 = -1e30f;                       // cols 49..63 masked
            float mx = fmaxf(fmaxf(v0, v1), fmaxf(v2, v3));
            #pragma unroll
            for (int off = 1; off < 16; off <<= 1) mx = fmaxf(mx, __shfl_xor(mx, off));
            float e0 = __expf(v0 - mx), e1 = __expf(v1 - mx);
            float e2 = __expf(v2 - mx), e3 = __expf(v3 - mx); // masked -> 0
            float sm = e0 + e1 + e2 + e3;
            #pragma unroll
            for (int off = 1; off < 16; off <<= 1) sm += __shfl_xor(sm, off);
            rcp[mt * 4 + r] = 1.0f / sm;
            int row = mt * 16 + fq * 4 + r;
            lds[base + row * 72 + 0 * 16 + fm]  = bfr(e0);
            lds[base + row * 72 + 1 * 16 + fm]  = bfr(e1);
            lds[base + row * 72 + 2 * 16 + fm]  = bfr(e2);
            lds[base + row * 72 + 3 * 16 + fm]  = bfr(e3);
        }
    }

    // O = P @ V   (V^T staged as B operand; k = l2, two k-steps)
    f4v O[4][2] = {};
    #pragma unroll
    for (int kt = 0; kt < 2; ++kt) {
        s8v Pf[4], Vf[2];
        #pragma unroll
        for (int mt = 0; mt < 4; ++mt)
            Pf[mt] = *reinterpret_cast<const s8v*>(&lds[base + (mt * 16 + fm) * 72 + kt * 32 + fq * 8]);
        #pragma unroll
        for (int nt = 0; nt < 2; ++nt)
            Vf[nt] = *reinterpret_cast<const s8v*>(&lds[base + 5120 + (nt * 16 + fm) * 72 + kt * 32 + fq * 8]);
        #pragma unroll
        for (int mt = 0; mt < 4; ++mt)
            #pragma unroll
            for (int nt = 0; nt < 2; ++nt)
                O[mt][nt] = __builtin_amdgcn_mfma_f32_16x16x32_bf16(Pf[mt], Vf[nt], O[mt][nt], 0, 0, 0);
    }

    float* ob = o + (size_t)win * 49 * 128 + h * 32;
    #pragma unroll
    for (int mt = 0; mt < 4; ++mt)
        #pragma unroll
        for (int r = 0; r < 4; ++r) {
            int row = mt * 16 + fq * 4 + r;
            if (row < 49) {
                float sc = rcp[mt * 4 + r];
                ob[(size_t)row * 128 + 0 * 16 + fm] = O[mt][0][r] * sc;
                ob[(size_t)row * 128 + 1 * 16 + fm] = O[mt][1][r] * sc;
            }
        }
}

extern "C" void kernel_launch(void* const* d_in, const int* in_sizes, int n_in,
                              void* d_out, int out_size, void* d_ws, size_t ws_size,
                              hipStream_t stream) {
    const float* x    = (const float*)d_in[0];
    const float* n1g  = (const float*)d_in[1];
    const float* n1b  = (const float*)d_in[2];
    const float* qkvw = (const float*)d_in[3];
    const float* qkvb = (const float*)d_in[4];
    const float* outw = (const float*)d_in[5];
    const float* outb = (const float*)d_in[6];
    const float* pe   = (const float*)d_in[7];
    const float* n2g  = (const float*)d_in[8];
    const float* n2b  = (const float*)d_in[9];
    const float* w1   = (const float*)d_in[10];
    const float* b1   = (const float*)d_in[11];
    const float* w2   = (const float*)d_in[12];
    const float* b2   = (const float*)d_in[13];
    float* y = (float*)d_out;

    size_t wpc = NWIN;
    while (wpc > 8 && 65536 + wpc * 49 * 2560 > ws_size) wpc >>= 1;
    const int nchunks = (int)(NWIN / wpc);
    const size_t rows = wpc * 49;

    char* ws = (char*)d_ws;
    float* btab = (float*)ws;                            // 64 KB
    float* bufA = (float*)(ws + 65536);                  // rows x 128
    float* bufB = (float*)(ws + 65536 + rows * 512);     // rows x 512
    const int gy = (int)((rows + 63) / 64);

    bias_tab_kernel<<<1, 256, 0, stream>>>(pe, btab);

    for (int c = 0; c < nchunks; ++c) {
        int tbase = (int)(c * wpc * 49);
        ln_kernel<<<(int)(rows / 4), 256, 0, stream>>>(x, n1g, n1b, bufA, 0, tbase);
        gemm_mfma<<<dim3(6, gy), 256, 0, stream>>>(bufA, qkvw, qkvb, bufB, (int)rows, 384, 128, 0, 0, 0);
        attn_mfma<<<(int)wpc, 256, 0, stream>>>(bufB, btab, bufA);
        gemm_mfma<<<dim3(2, gy), 256, 0, stream>>>(bufA, outw, outb, bufB, (int)rows, 128, 128, 0, 0, 0);
        ln_kernel<<<(int)(rows / 4), 256, 0, stream>>>(bufB, n2g, n2b, bufA, 1, 0);
        gemm_mfma<<<dim3(8, gy), 256, 0, stream>>>(bufA, w1, b1, bufB, (int)rows, 512, 128, 1, 0, 0);
        gemm_mfma<<<dim3(2, gy), 256, 0, stream>>>(bufB, w2, b2, y, (int)rows, 128, 512, 0, 1, tbase);
    }
}